// Round 1
// baseline (298.919 us; speedup 1.0000x reference)
//
#include <hip/hip_runtime.h>
#include <math.h>

#define NN   4096            // N = V*B
#define BD   2048            // B
#define DF   128             // D
#define INV_T (1.0f/0.07f)

// ---------------- Kernel 1: normalize features, zero Z ----------------
__global__ void k_prep(const float* __restrict__ feat, float* __restrict__ f,
                       float* __restrict__ Zv) {
  int gid  = blockIdx.x * blockDim.x + threadIdx.x;   // 1024*256 = 262144
  int row  = gid >> 6;                                // one wave per row
  int lane = threadIdx.x & 63;
  const float2* src = (const float2*)(feat + (size_t)row * DF);
  float2 v = src[lane];
  float ss = v.x * v.x + v.y * v.y;
  #pragma unroll
  for (int off = 1; off < 64; off <<= 1) ss += __shfl_xor(ss, off, 64);
  float inv = rsqrtf(ss);
  float2 o; o.x = v.x * inv; o.y = v.y * inv;
  ((float2*)(f + (size_t)row * DF))[lane] = o;
  if (gid < NN) Zv[gid] = 0.f;
}

// ---------------- Kernel 2: sparsemax per row (one wave per row) ----------------
// z_j = negmask ? attn_ij/T : 0 ; solve sum(max(z-tau,0)) = 1 by bisection
// tau in [m1-1, m1), then exact support refinement. Writes ms to out+1, tau to ws.
__global__ void k_sparsemax(const float* __restrict__ attn,
                            float* __restrict__ msOut,   // d_out + 1
                            float* __restrict__ tauOut) {
  int row  = (blockIdx.x * blockDim.x + threadIdx.x) >> 6;
  int lane = threadIdx.x & 63;
  const float* arow = attn + (size_t)row * NN;
  int rb = row & (BD - 1);
  float z[64];
  float m1 = -1e30f;
  #pragma unroll
  for (int u = 0; u < 64; ++u) {
    int j = lane + 64 * u;
    float a = arow[j];
    float zz = ((j & (BD - 1)) == rb) ? 0.f : a * INV_T;
    z[u] = zz;
    m1 = fmaxf(m1, zz);
  }
  #pragma unroll
  for (int off = 1; off < 64; off <<= 1) m1 = fmaxf(m1, __shfl_xor(m1, off, 64));

  float lo = m1 - 1.0f, hi = m1;
  #pragma unroll 1
  for (int it = 0; it < 26; ++it) {
    float mid = 0.5f * (lo + hi);
    float g0 = 0.f, g1 = 0.f, g2 = 0.f, g3 = 0.f;
    #pragma unroll
    for (int u = 0; u < 64; u += 4) {
      g0 += fmaxf(z[u]     - mid, 0.f);
      g1 += fmaxf(z[u + 1] - mid, 0.f);
      g2 += fmaxf(z[u + 2] - mid, 0.f);
      g3 += fmaxf(z[u + 3] - mid, 0.f);
    }
    float g = (g0 + g1) + (g2 + g3);
    #pragma unroll
    for (int off = 1; off < 64; off <<= 1) g += __shfl_xor(g, off, 64);
    if (g >= 1.0f) lo = mid; else hi = mid;
  }
  float mid = 0.5f * (lo + hi);
  float s = 0.f, c = 0.f;
  #pragma unroll
  for (int u = 0; u < 64; ++u) {
    if (z[u] > mid) { s += z[u]; c += 1.f; }
  }
  #pragma unroll
  for (int off = 1; off < 64; off <<= 1) {
    s += __shfl_xor(s, off, 64);
    c += __shfl_xor(c, off, 64);
  }
  float tau = (c > 0.f) ? (s - 1.0f) / c : mid;
  if (lane == 0) tauOut[row] = tau;

  float* orow = msOut + (size_t)row * NN;
  #pragma unroll
  for (int u = 0; u < 64; ++u) {
    int j = lane + 64 * u;
    orow[j] = fmaxf(z[u] - tau, 0.f);
  }
}

// ---------------- Kernel 3: fused Gram + Z reduction ----------------
// grid (8, 64): block handles rows [64*by, 64*by+64), cols [512*bx, 512*bx+512)
// sim_ij = dot(f_i,f_j)/T ; m = 1/T (diag is row max) ;
// Z_i += exp(sim - m) * ((i!=j) - ms_ij), ms recomputed from attn + tau (bit-exact).
#define TM 64
#define TJ 64
#define LDP 132   // padded LDS row stride (floats), multiple of 4
__global__ __launch_bounds__(256) void k_gram(
    const float* __restrict__ f, const float* __restrict__ attn,
    const float* __restrict__ tau, float* __restrict__ Zv,
    float* __restrict__ numer) {
  __shared__ float As[TM][LDP];
  __shared__ float Bs[TJ][LDP];
  int i0 = blockIdx.y * TM;
  int jbase = blockIdx.x * (NN / 8);
  int tid = threadIdx.x;
  int tx = tid & 15, ty = tid >> 4;

  // stage A rows (64 x 128 floats) once
  #pragma unroll
  for (int it = 0; it < 8; ++it) {
    int flat = (it * 256 + tid) * 4;
    int r = flat >> 7, c = flat & 127;
    *(float4*)(&As[r][c]) = *(const float4*)(f + (size_t)(i0 + r) * DF + c);
  }

  float taum[4];
  #pragma unroll
  for (int m = 0; m < 4; ++m) taum[m] = tau[i0 + ty + 16 * m];

  float zacc[4] = {0.f, 0.f, 0.f, 0.f};

  for (int jt = 0; jt < NN / 8; jt += TJ) {
    int j0 = jbase + jt;
    __syncthreads();
    #pragma unroll
    for (int it = 0; it < 8; ++it) {
      int flat = (it * 256 + tid) * 4;
      int r = flat >> 7, c = flat & 127;
      *(float4*)(&Bs[r][c]) = *(const float4*)(f + (size_t)(j0 + r) * DF + c);
    }
    __syncthreads();

    float acc[4][4];
    #pragma unroll
    for (int m = 0; m < 4; ++m)
      #pragma unroll
      for (int n = 0; n < 4; ++n) acc[m][n] = 0.f;

    #pragma unroll 4
    for (int k = 0; k < DF; k += 4) {
      float4 a[4], b[4];
      #pragma unroll
      for (int m = 0; m < 4; ++m) a[m] = *(float4*)(&As[ty + 16 * m][k]);
      #pragma unroll
      for (int n = 0; n < 4; ++n) b[n] = *(float4*)(&Bs[tx + 16 * n][k]);
      #pragma unroll
      for (int m = 0; m < 4; ++m)
        #pragma unroll
        for (int n = 0; n < 4; ++n)
          acc[m][n] += a[m].x * b[n].x + a[m].y * b[n].y +
                       a[m].z * b[n].z + a[m].w * b[n].w;
    }

    // epilogue for this 64x64 tile
    #pragma unroll
    for (int m = 0; m < 4; ++m) {
      int i = i0 + ty + 16 * m;
      #pragma unroll
      for (int n = 0; n < 4; ++n) {
        int j = j0 + tx + 16 * n;
        float sim = acc[m][n] * INV_T;
        float a = attn[(size_t)i * NN + j];
        float zval = (((j ^ i) & (BD - 1)) == 0) ? 0.f : a * INV_T;
        float ms = fmaxf(zval - taum[m], 0.f);
        float w = ((i == j) ? 0.f : 1.f) - ms;
        zacc[m] += __expf(sim - INV_T) * w;
        if (j == ((i + BD) & (NN - 1))) numer[i] = sim - INV_T;
      }
    }
  }

  // reduce zacc over the 16 tx lanes of each ty group, one atomic per row
  #pragma unroll
  for (int m = 0; m < 4; ++m) {
    float v = zacc[m];
    v += __shfl_xor(v, 1, 64);
    v += __shfl_xor(v, 2, 64);
    v += __shfl_xor(v, 4, 64);
    v += __shfl_xor(v, 8, 64);
    if (tx == 0) atomicAdd(&Zv[i0 + ty + 16 * m], v);
  }
}

// ---------------- Kernel 4: finalize loss (single block) ----------------
__global__ void k_loss(const float* __restrict__ Zv,
                       const float* __restrict__ numer,
                       float* __restrict__ out) {
  float acc = 0.f;
  for (int i = threadIdx.x; i < NN; i += 256)
    acc += numer[i] - logf(Zv[i]);
  #pragma unroll
  for (int off = 1; off < 64; off <<= 1) acc += __shfl_xor(acc, off, 64);
  __shared__ float red[4];
  int wv = threadIdx.x >> 6, lane = threadIdx.x & 63;
  if (lane == 0) red[wv] = acc;
  __syncthreads();
  if (threadIdx.x == 0) {
    float t = (red[0] + red[1]) + (red[2] + red[3]);
    out[0] = -t / (float)NN;
  }
}

extern "C" void kernel_launch(void* const* d_in, const int* in_sizes, int n_in,
                              void* d_out, int out_size, void* d_ws, size_t ws_size,
                              hipStream_t stream) {
  const float* feat = (const float*)d_in[0];   // (2048, 2, 128) f32 -> (4096,128)
  const float* attn = (const float*)d_in[1];   // (4096, 4096) f32
  float* out = (float*)d_out;                  // [loss, masked_scores(16.7M)]
  float* msOut = out + 1;

  float* f     = (float*)d_ws;                 // N*D
  float* tauv  = f + (size_t)NN * DF;          // N
  float* Zv    = tauv + NN;                    // N
  float* numer = Zv + NN;                      // N

  k_prep<<<dim3(1024), dim3(256), 0, stream>>>(feat, f, Zv);
  k_sparsemax<<<dim3(1024), dim3(256), 0, stream>>>(attn, msOut, tauv);
  k_gram<<<dim3(8, 64), dim3(256), 0, stream>>>(f, attn, tauv, Zv, numer);
  k_loss<<<dim3(1), dim3(256), 0, stream>>>(Zv, numer, out);
}

// Round 2
// 217.810 us; speedup vs baseline: 1.3724x; 1.3724x over previous
//
#include <hip/hip_runtime.h>
#include <math.h>

#define NN   4096            // N = V*B
#define BD   2048            // B
#define DF   128             // D
#define INV_T (1.0f/0.07f)

// ---------------- Kernel 1: normalize features, zero Z ----------------
__global__ void k_prep(const float* __restrict__ feat, float* __restrict__ f,
                       float* __restrict__ Zv) {
  int gid  = blockIdx.x * blockDim.x + threadIdx.x;   // 1024*256 = 262144
  int row  = gid >> 6;                                // one wave per row
  int lane = threadIdx.x & 63;
  const float2* src = (const float2*)(feat + (size_t)row * DF);
  float2 v = src[lane];
  float ss = v.x * v.x + v.y * v.y;
  #pragma unroll
  for (int off = 1; off < 64; off <<= 1) ss += __shfl_xor(ss, off, 64);
  float inv = rsqrtf(ss);
  float2 o; o.x = v.x * inv; o.y = v.y * inv;
  ((float2*)(f + (size_t)row * DF))[lane] = o;
  if (gid < NN) Zv[gid] = 0.f;
}

// ---------------- Kernel 2: sparsemax per row ----------------
// One 256-thread block per row; z[16] per thread stays in VGPRs (no spill).
// Newton iteration tau' = (sum_{z>tau} z - 1)/|{z>tau}| from tau0 = max-1:
// g(tau) = sum max(z-tau,0) - 1 is convex piecewise-linear, Newton from the
// left converges monotonically and exactly (== support-set refinement).
__global__ __launch_bounds__(256) void k_sparsemax(
    const float* __restrict__ attn,
    float* __restrict__ msOut,   // d_out + 1
    float* __restrict__ tauOut) {
  __shared__ float redS[4], redC[4];
  int row  = blockIdx.x;
  int tid  = threadIdx.x;
  int lane = tid & 63, wv = tid >> 6;
  const float4* arow = (const float4*)(attn + (size_t)row * NN);
  int rb = row & (BD - 1);
  float z[16];
  #pragma unroll
  for (int u = 0; u < 4; ++u) {
    int q = u * 256 + tid;            // float4 index: perfectly coalesced
    float4 a = arow[q];
    int j = q * 4;
    z[4*u+0] = (((j+0) & (BD-1)) == rb) ? 0.f : a.x * INV_T;
    z[4*u+1] = (((j+1) & (BD-1)) == rb) ? 0.f : a.y * INV_T;
    z[4*u+2] = (((j+2) & (BD-1)) == rb) ? 0.f : a.z * INV_T;
    z[4*u+3] = (((j+3) & (BD-1)) == rb) ? 0.f : a.w * INV_T;
  }
  // row max
  float m = z[0];
  #pragma unroll
  for (int u = 1; u < 16; ++u) m = fmaxf(m, z[u]);
  #pragma unroll
  for (int off = 1; off < 64; off <<= 1) m = fmaxf(m, __shfl_xor(m, off, 64));
  if (lane == 0) redS[wv] = m;
  __syncthreads();
  m = fmaxf(fmaxf(redS[0], redS[1]), fmaxf(redS[2], redS[3]));

  float tau = m - 1.0f;
  #pragma unroll 1
  for (int it = 0; it < 8; ++it) {
    float S = 0.f, C = 0.f;
    #pragma unroll
    for (int u = 0; u < 16; ++u) {
      bool in = z[u] > tau;
      S += in ? z[u] : 0.f;
      C += in ? 1.f : 0.f;
    }
    #pragma unroll
    for (int off = 1; off < 64; off <<= 1) {
      S += __shfl_xor(S, off, 64);
      C += __shfl_xor(C, off, 64);
    }
    __syncthreads();                    // protect redS/redC reuse
    if (lane == 0) { redS[wv] = S; redC[wv] = C; }
    __syncthreads();
    S = (redS[0] + redS[1]) + (redS[2] + redS[3]);
    C = (redC[0] + redC[1]) + (redC[2] + redC[3]);
    tau = (C > 0.f) ? (S - 1.0f) / C : tau;
  }
  if (tid == 0) tauOut[row] = tau;

  // store ms = max(z - tau, 0). msOut is d_out+1 (4B-aligned only) -> scalar
  // stores; each thread writes 4 consecutive floats, wave covers contiguous
  // 4 KB region, fully-covered cachelines.
  float* orow = msOut + (size_t)row * NN;
  #pragma unroll
  for (int u = 0; u < 4; ++u) {
    int j = (u * 256 + tid) * 4;
    orow[j+0] = fmaxf(z[4*u+0] - tau, 0.f);
    orow[j+1] = fmaxf(z[4*u+1] - tau, 0.f);
    orow[j+2] = fmaxf(z[4*u+2] - tau, 0.f);
    orow[j+3] = fmaxf(z[4*u+3] - tau, 0.f);
  }
}

// ---------------- Kernel 3: fused Gram + Z reduction ----------------
// grid (8, 64): block handles rows [64*by, 64*by+64), cols [512*bx, 512*bx+512)
// sim_ij = dot(f_i,f_j)/T ; m = 1/T (diag is row max) ;
// Z_i += exp(sim - m) * ((i!=j) - ms_ij), ms recomputed from attn + tau (bit-exact).
#define TM 64
#define TJ 64
#define LDP 132   // padded LDS row stride (floats), multiple of 4
__global__ __launch_bounds__(256) void k_gram(
    const float* __restrict__ f, const float* __restrict__ attn,
    const float* __restrict__ tau, float* __restrict__ Zv,
    float* __restrict__ numer) {
  __shared__ float As[TM][LDP];
  __shared__ float Bs[TJ][LDP];
  int i0 = blockIdx.y * TM;
  int jbase = blockIdx.x * (NN / 8);
  int tid = threadIdx.x;
  int tx = tid & 15, ty = tid >> 4;

  // stage A rows (64 x 128 floats) once
  #pragma unroll
  for (int it = 0; it < 8; ++it) {
    int flat = (it * 256 + tid) * 4;
    int r = flat >> 7, c = flat & 127;
    *(float4*)(&As[r][c]) = *(const float4*)(f + (size_t)(i0 + r) * DF + c);
  }

  float taum[4];
  #pragma unroll
  for (int m = 0; m < 4; ++m) taum[m] = tau[i0 + ty + 16 * m];

  float zacc[4] = {0.f, 0.f, 0.f, 0.f};

  for (int jt = 0; jt < NN / 8; jt += TJ) {
    int j0 = jbase + jt;
    __syncthreads();
    #pragma unroll
    for (int it = 0; it < 8; ++it) {
      int flat = (it * 256 + tid) * 4;
      int r = flat >> 7, c = flat & 127;
      *(float4*)(&Bs[r][c]) = *(const float4*)(f + (size_t)(j0 + r) * DF + c);
    }
    __syncthreads();

    float acc[4][4];
    #pragma unroll
    for (int m = 0; m < 4; ++m)
      #pragma unroll
      for (int n = 0; n < 4; ++n) acc[m][n] = 0.f;

    #pragma unroll 4
    for (int k = 0; k < DF; k += 4) {
      float4 a[4], b[4];
      #pragma unroll
      for (int m = 0; m < 4; ++m) a[m] = *(float4*)(&As[ty + 16 * m][k]);
      #pragma unroll
      for (int n = 0; n < 4; ++n) b[n] = *(float4*)(&Bs[tx + 16 * n][k]);
      #pragma unroll
      for (int m = 0; m < 4; ++m)
        #pragma unroll
        for (int n = 0; n < 4; ++n)
          acc[m][n] += a[m].x * b[n].x + a[m].y * b[n].y +
                       a[m].z * b[n].z + a[m].w * b[n].w;
    }

    // epilogue for this 64x64 tile
    #pragma unroll
    for (int m = 0; m < 4; ++m) {
      int i = i0 + ty + 16 * m;
      #pragma unroll
      for (int n = 0; n < 4; ++n) {
        int j = j0 + tx + 16 * n;
        float sim = acc[m][n] * INV_T;
        float a = attn[(size_t)i * NN + j];
        float zval = (((j ^ i) & (BD - 1)) == 0) ? 0.f : a * INV_T;
        float ms = fmaxf(zval - taum[m], 0.f);
        float w = ((i == j) ? 0.f : 1.f) - ms;
        zacc[m] += __expf(sim - INV_T) * w;
        if (j == ((i + BD) & (NN - 1))) numer[i] = sim - INV_T;
      }
    }
  }

  // reduce zacc over the 16 tx lanes of each ty group, one atomic per row
  #pragma unroll
  for (int m = 0; m < 4; ++m) {
    float v = zacc[m];
    v += __shfl_xor(v, 1, 64);
    v += __shfl_xor(v, 2, 64);
    v += __shfl_xor(v, 4, 64);
    v += __shfl_xor(v, 8, 64);
    if (tx == 0) atomicAdd(&Zv[i0 + ty + 16 * m], v);
  }
}

// ---------------- Kernel 4: finalize loss (single block) ----------------
__global__ void k_loss(const float* __restrict__ Zv,
                       const float* __restrict__ numer,
                       float* __restrict__ out) {
  float acc = 0.f;
  for (int i = threadIdx.x; i < NN; i += 256)
    acc += numer[i] - logf(Zv[i]);
  #pragma unroll
  for (int off = 1; off < 64; off <<= 1) acc += __shfl_xor(acc, off, 64);
  __shared__ float red[4];
  int wv = threadIdx.x >> 6, lane = threadIdx.x & 63;
  if (lane == 0) red[wv] = acc;
  __syncthreads();
  if (threadIdx.x == 0) {
    float t = (red[0] + red[1]) + (red[2] + red[3]);
    out[0] = -t / (float)NN;
  }
}

extern "C" void kernel_launch(void* const* d_in, const int* in_sizes, int n_in,
                              void* d_out, int out_size, void* d_ws, size_t ws_size,
                              hipStream_t stream) {
  const float* feat = (const float*)d_in[0];   // (2048, 2, 128) f32 -> (4096,128)
  const float* attn = (const float*)d_in[1];   // (4096, 4096) f32
  float* out = (float*)d_out;                  // [loss, masked_scores(16.7M)]
  float* msOut = out + 1;

  float* f     = (float*)d_ws;                 // N*D
  float* tauv  = f + (size_t)NN * DF;          // N
  float* Zv    = tauv + NN;                    // N
  float* numer = Zv + NN;                      // N

  k_prep<<<dim3(1024), dim3(256), 0, stream>>>(feat, f, Zv);
  k_sparsemax<<<dim3(4096), dim3(256), 0, stream>>>(attn, msOut, tauv);
  k_gram<<<dim3(8, 64), dim3(256), 0, stream>>>(f, attn, tauv, Zv, numer);
  k_loss<<<dim3(1), dim3(256), 0, stream>>>(Zv, numer, out);
}

// Round 3
// 172.646 us; speedup vs baseline: 1.7314x; 1.2616x over previous
//
#include <hip/hip_runtime.h>
#include <math.h>

#define NN   4096            // N = V*B
#define BD   2048            // B
#define DF   128             // D
#define INV_T (1.0f/0.07f)

typedef __attribute__((ext_vector_type(8))) short short8v;   // 8 x bf16
typedef __attribute__((ext_vector_type(4))) float float4v;

__device__ inline unsigned short f2bf_rne(float x) {
  unsigned int u = __float_as_uint(x);
  u = (u + 0x7FFFu + ((u >> 16) & 1u)) >> 16;
  return (unsigned short)u;
}

// ---------------- Kernel 1: normalize features -> bf16, zero Z ----------------
__global__ void k_prep(const float* __restrict__ feat,
                       unsigned short* __restrict__ fbf,
                       float* __restrict__ Zv) {
  int gid  = blockIdx.x * blockDim.x + threadIdx.x;   // 1024*256 = 262144
  int row  = gid >> 6;                                // one wave per row
  int lane = threadIdx.x & 63;
  const float2* src = (const float2*)(feat + (size_t)row * DF);
  float2 v = src[lane];
  float ss = v.x * v.x + v.y * v.y;
  #pragma unroll
  for (int off = 1; off < 64; off <<= 1) ss += __shfl_xor(ss, off, 64);
  float inv = rsqrtf(ss);
  ushort2 o;
  o.x = f2bf_rne(v.x * inv);
  o.y = f2bf_rne(v.y * inv);
  ((ushort2*)(fbf + (size_t)row * DF))[lane] = o;
  if (gid < NN) Zv[gid] = 0.f;
}

// ---------------- Kernel 2: sparsemax per row (unchanged) ----------------
__global__ __launch_bounds__(256) void k_sparsemax(
    const float* __restrict__ attn,
    float* __restrict__ msOut,   // d_out + 1
    float* __restrict__ tauOut) {
  __shared__ float redS[4], redC[4];
  int row  = blockIdx.x;
  int tid  = threadIdx.x;
  int lane = tid & 63, wv = tid >> 6;
  const float4* arow = (const float4*)(attn + (size_t)row * NN);
  int rb = row & (BD - 1);
  float z[16];
  #pragma unroll
  for (int u = 0; u < 4; ++u) {
    int q = u * 256 + tid;            // float4 index: perfectly coalesced
    float4 a = arow[q];
    int j = q * 4;
    z[4*u+0] = (((j+0) & (BD-1)) == rb) ? 0.f : a.x * INV_T;
    z[4*u+1] = (((j+1) & (BD-1)) == rb) ? 0.f : a.y * INV_T;
    z[4*u+2] = (((j+2) & (BD-1)) == rb) ? 0.f : a.z * INV_T;
    z[4*u+3] = (((j+3) & (BD-1)) == rb) ? 0.f : a.w * INV_T;
  }
  float m = z[0];
  #pragma unroll
  for (int u = 1; u < 16; ++u) m = fmaxf(m, z[u]);
  #pragma unroll
  for (int off = 1; off < 64; off <<= 1) m = fmaxf(m, __shfl_xor(m, off, 64));
  if (lane == 0) redS[wv] = m;
  __syncthreads();
  m = fmaxf(fmaxf(redS[0], redS[1]), fmaxf(redS[2], redS[3]));

  float tau = m - 1.0f;
  #pragma unroll 1
  for (int it = 0; it < 8; ++it) {
    float S = 0.f, C = 0.f;
    #pragma unroll
    for (int u = 0; u < 16; ++u) {
      bool in = z[u] > tau;
      S += in ? z[u] : 0.f;
      C += in ? 1.f : 0.f;
    }
    #pragma unroll
    for (int off = 1; off < 64; off <<= 1) {
      S += __shfl_xor(S, off, 64);
      C += __shfl_xor(C, off, 64);
    }
    __syncthreads();
    if (lane == 0) { redS[wv] = S; redC[wv] = C; }
    __syncthreads();
    S = (redS[0] + redS[1]) + (redS[2] + redS[3]);
    C = (redC[0] + redC[1]) + (redC[2] + redC[3]);
    tau = (C > 0.f) ? (S - 1.0f) / C : tau;
  }
  if (tid == 0) tauOut[row] = tau;

  float* orow = msOut + (size_t)row * NN;
  #pragma unroll
  for (int u = 0; u < 4; ++u) {
    int j = (u * 256 + tid) * 4;
    orow[j+0] = fmaxf(z[4*u+0] - tau, 0.f);
    orow[j+1] = fmaxf(z[4*u+1] - tau, 0.f);
    orow[j+2] = fmaxf(z[4*u+2] - tau, 0.f);
    orow[j+3] = fmaxf(z[4*u+3] - tau, 0.f);
  }
}

// ---------------- Kernel 3: MFMA Gram + fused Z reduction ----------------
// Gram = F · F^T with F (4096x128) bf16, L2-resident (1 MB) -> no LDS.
// Block = 4 waves in 2x2 -> 128x128 C-tile; wave computes 64x64 via 4x4
// frags of mfma_f32_16x16x32_bf16 over K=128 (4 k-steps).
// A frag: lane holds A[m=lane&15][k=quad*8+j]; B frag: B[k][n=lane&15] =
// f[n][k] -> identical row-load pattern (Gram/B^T case).
// C/D: col=lane&15, row=quad*4+reg.
__global__ __launch_bounds__(256) void k_gram(
    const unsigned short* __restrict__ fbf, const float* __restrict__ attn,
    const float* __restrict__ tau, float* __restrict__ Zv,
    float* __restrict__ numer) {
  int tid = threadIdx.x;
  int wave = tid >> 6, lane = tid & 63;
  int c = lane & 15, quad = lane >> 4;
  int wi = wave >> 1, wj = wave & 1;
  int i0 = blockIdx.y * 128 + wi * 64;
  int j0 = blockIdx.x * 128 + wj * 64;

  const unsigned short* aBase = fbf + (size_t)(i0 + c) * DF + quad * 8;
  const unsigned short* bBase = fbf + (size_t)(j0 + c) * DF + quad * 8;

  float4v acc[4][4];
  #pragma unroll
  for (int m = 0; m < 4; ++m)
    #pragma unroll
    for (int n = 0; n < 4; ++n) acc[m][n] = (float4v){0.f, 0.f, 0.f, 0.f};

  #pragma unroll
  for (int k0 = 0; k0 < DF; k0 += 32) {
    short8v afr[4], bfr[4];
    #pragma unroll
    for (int m = 0; m < 4; ++m)
      afr[m] = *(const short8v*)(aBase + (size_t)(m * 16) * DF + k0);
    #pragma unroll
    for (int n = 0; n < 4; ++n)
      bfr[n] = *(const short8v*)(bBase + (size_t)(n * 16) * DF + k0);
    #pragma unroll
    for (int m = 0; m < 4; ++m)
      #pragma unroll
      for (int n = 0; n < 4; ++n)
        acc[m][n] = __builtin_amdgcn_mfma_f32_16x16x32_bf16(
            afr[m], bfr[n], acc[m][n], 0, 0, 0);
  }

  // epilogue: Z_i += exp(sim - 1/T) * ((i!=j) - ms_ij); numer_i at positive col
  #pragma unroll
  for (int m = 0; m < 4; ++m) {
    #pragma unroll
    for (int r = 0; r < 4; ++r) {
      int i = i0 + m * 16 + quad * 4 + r;
      float taui = tau[i];
      float zsum = 0.f;
      #pragma unroll
      for (int n = 0; n < 4; ++n) {
        int j = j0 + n * 16 + c;
        float simv = acc[m][n][r] * INV_T - INV_T;
        float a = attn[(size_t)i * NN + j];
        float zval = (((j ^ i) & (BD - 1)) == 0) ? 0.f : a * INV_T;
        float ms = fmaxf(zval - taui, 0.f);
        float w = ((i == j) ? 0.f : 1.f) - ms;
        zsum += __expf(simv) * w;
        if (j == ((i + BD) & (NN - 1))) numer[i] = simv;
      }
      zsum += __shfl_xor(zsum, 1, 64);
      zsum += __shfl_xor(zsum, 2, 64);
      zsum += __shfl_xor(zsum, 4, 64);
      zsum += __shfl_xor(zsum, 8, 64);
      if (c == 0) atomicAdd(&Zv[i], zsum);
    }
  }
}

// ---------------- Kernel 4: finalize loss (single block) ----------------
__global__ void k_loss(const float* __restrict__ Zv,
                       const float* __restrict__ numer,
                       float* __restrict__ out) {
  float acc = 0.f;
  for (int i = threadIdx.x; i < NN; i += 256)
    acc += numer[i] - logf(Zv[i]);
  #pragma unroll
  for (int off = 1; off < 64; off <<= 1) acc += __shfl_xor(acc, off, 64);
  __shared__ float red[4];
  int wv = threadIdx.x >> 6, lane = threadIdx.x & 63;
  if (lane == 0) red[wv] = acc;
  __syncthreads();
  if (threadIdx.x == 0) {
    float t = (red[0] + red[1]) + (red[2] + red[3]);
    out[0] = -t / (float)NN;
  }
}

extern "C" void kernel_launch(void* const* d_in, const int* in_sizes, int n_in,
                              void* d_out, int out_size, void* d_ws, size_t ws_size,
                              hipStream_t stream) {
  const float* feat = (const float*)d_in[0];   // (2048, 2, 128) f32 -> (4096,128)
  const float* attn = (const float*)d_in[1];   // (4096, 4096) f32
  float* out = (float*)d_out;                  // [loss, masked_scores(16.7M)]
  float* msOut = out + 1;

  float* tauv  = (float*)d_ws;                 // N
  float* Zv    = tauv + NN;                    // N
  float* numer = Zv + NN;                      // N
  unsigned short* fbf = (unsigned short*)(numer + NN);  // N*D bf16

  k_prep<<<dim3(1024), dim3(256), 0, stream>>>(feat, fbf, Zv);
  k_sparsemax<<<dim3(4096), dim3(256), 0, stream>>>(attn, msOut, tauv);
  k_gram<<<dim3(32, 32), dim3(256), 0, stream>>>(fbf, attn, tauv, Zv, numer);
  k_loss<<<dim3(1), dim3(256), 0, stream>>>(Zv, numer, out);
}